// Round 8
// baseline (140.531 us; speedup 1.0000x reference)
//
#include <hip/hip_runtime.h>
#include <hip/hip_bf16.h>
#include <cstdint>
#include <math.h>

#define D_DIM 1024
#define TAU_INV 10.0f
#define BK 32
#define NT (D_DIM / BK)        // 32 K-tiles
#define BM 256                 // A-tile rows
#define BN 256                 // B-tile rows (cols of S)
#define SLOT 32768             // ring slot: A 16K + B 16K

typedef __bf16 bf16x8 __attribute__((ext_vector_type(8)));
typedef float f32x4 __attribute__((ext_vector_type(4)));

#define VMCNT(n) asm volatile("s_waitcnt vmcnt(" #n ")" ::: "memory")
#define BAR() do { asm volatile("" ::: "memory"); \
                   __builtin_amdgcn_s_barrier();  \
                   asm volatile("" ::: "memory"); } while (0)
#define LGKM0() do { asm volatile("s_waitcnt lgkmcnt(0)" ::: "memory"); \
                     __builtin_amdgcn_sched_barrier(0); } while (0)

__device__ __forceinline__ float wave_reduce_add(float v) {
#pragma unroll
    for (int off = 32; off > 0; off >>= 1) v += __shfl_xor(v, off, 64);
    return v;
}

// ---- Kernel A (fused): normalize both rows -> bf16 K, positives, zero rowsum
__global__ __launch_bounds__(256)
void norm_pos_kernel(const float* __restrict__ zi, const float* __restrict__ zj,
                     __hip_bfloat16* __restrict__ K, float* __restrict__ rowsum,
                     float* __restrict__ pos, int n_half) {
    const int i = blockIdx.x;
    const int t = threadIdx.x;                 // 256 threads x 4 floats = 1024
    float4 a = reinterpret_cast<const float4*>(zi + (size_t)i * D_DIM)[t];
    float4 b = reinterpret_cast<const float4*>(zj + (size_t)i * D_DIM)[t];
    float ssa = a.x*a.x + a.y*a.y + a.z*a.z + a.w*a.w;
    float ssb = b.x*b.x + b.y*b.y + b.z*b.z + b.w*b.w;
    float dab = a.x*b.x + a.y*b.y + a.z*b.z + a.w*b.w;
    ssa = wave_reduce_add(ssa);
    ssb = wave_reduce_add(ssb);
    dab = wave_reduce_add(dab);
    __shared__ float wsa[4], wsb[4], wsd[4];
    if ((t & 63) == 0) { wsa[t>>6] = ssa; wsb[t>>6] = ssb; wsd[t>>6] = dab; }
    __syncthreads();
    const float inva = 1.0f / sqrtf(wsa[0] + wsa[1] + wsa[2] + wsa[3]);
    const float invb = 1.0f / sqrtf(wsb[0] + wsb[1] + wsb[2] + wsb[3]);
    union { __hip_bfloat16 h[4]; uint2 u; } pa, pb;
    pa.h[0] = __float2bfloat16(a.x * inva); pa.h[1] = __float2bfloat16(a.y * inva);
    pa.h[2] = __float2bfloat16(a.z * inva); pa.h[3] = __float2bfloat16(a.w * inva);
    pb.h[0] = __float2bfloat16(b.x * invb); pb.h[1] = __float2bfloat16(b.y * invb);
    pb.h[2] = __float2bfloat16(b.z * invb); pb.h[3] = __float2bfloat16(b.w * invb);
    reinterpret_cast<uint2*>(K + (size_t)i * D_DIM)[t] = pa.u;
    reinterpret_cast<uint2*>(K + (size_t)(i + n_half) * D_DIM)[t] = pb.u;
    if (t == 0) {
        pos[i] = (wsd[0] + wsd[1] + wsd[2] + wsd[3]) * inva * invb;
        rowsum[i] = 0.0f;
        rowsum[i + n_half] = 0.0f;
    }
}

// ---- Kernel B: upper-triangular 256x256 tiles of S = K K^T -----------------
// 528 jobs (by <= bx < 32). diag (bx==by): row-reduction only, exact diagonal
// zeroed (both (r,c),(c,r) inside the tile). Off-diag: row + col reduction.
//
// 8 waves (2M x 4N), per-wave 128x64 output = acc[2(A-half)][4][4]; per K-tile
// (BK=32): 32 MFMA vs 12 ds_read_b128 per wave.
//
// Ring-4 LDS (4 x 32 KiB = 128 KiB), prefetch distance 3 K-tiles (~1200 cyc
// of compute cover vs ~600-900 cyc L3/HBM fill latency). Per K-tile, the
// R7-proven 2-phase discipline:
//   ph0: readB(4) + readA(half0,4)  [tile t published at BAR#2(t-1)]
//        BAR#1 ; lgkmcnt(0)+sched_barrier ; setprio(1) 16 MFMA setprio(0)
//   ph1: readA(half1,4) ; stage tile t+3 (4 gloads, slot (t-1)&3)
//        VMCNT(8) ; BAR#2 ; lgkmcnt(0)+sched_barrier ; 16 MFMA
// Residency induction: after VMCNT(8)@ph1(t), outstanding = stages{t+2,t+3}
// (8 loads) -> stage(t+1) complete -> BAR#2 publishes tile t+1. Base: prologue
// stages 0,1,2 then VMCNT(8) leaves {1,2} -> tile 0 resident. Tail: t==NT-3
// VMCNT(4), t==NT-2 VMCNT(0).
// Write-after-read: stage(t+3)@ph1(t) -> slot (t-1)&3, last read at ph1(t-1);
// every wave completes those reads at its LGKM0 after BAR#2(t-1), which
// precedes its arrival at BAR#1(t); stage is issued after BAR#1(t). (Race-free
// empirically since R4: absmax 0 across all dispatches.)
// LDS swizzle (R4/R7-verified, 0 conflicts): 16B slot_phys = kgrp^((row>>1)&3),
// inverse-applied on the global staging source (rule #21).
__global__ __launch_bounds__(512, 2)
void simclr_gemm_kernel(const __hip_bfloat16* __restrict__ Kmat,
                        float* __restrict__ rowsum, int n_total) {
    __shared__ char lds[131072];

    const int tid  = threadIdx.x;
    const int lane = tid & 63;
    const int wave = tid >> 6;          // 0..7
    const int wr = wave >> 2;           // 0..1  (A rows wr*128)
    const int wc = wave & 3;            // 0..3  (B cols wc*64)
    const int kgrp = lane >> 4;         // 16B k-slot within 64B row

    // bijective XCD banding: nwg = 528 = 8 * 66 (contiguous row-band per XCD)
    const int wg = (blockIdx.x & 7) * 66 + (blockIdx.x >> 3);

    // decode wg -> (by, bx), by <= bx < 32 (row-major triangular)
    int by = 0, start = 0;
    while (wg >= start + (32 - by)) { start += 32 - by; ++by; }
    const int bx = by + (wg - start);
    const bool diag = (bx == by);
    const int rowbase = by * BM;
    const int colbase = bx * BN;

    const char* gK = reinterpret_cast<const char*>(Kmat);
    const int srow = tid >> 2;                          // 0..127 per 8KB issue
    const int sswz = (tid & 3) ^ ((srow >> 1) & 3);     // inverse-swizzled slot

    // stage full K-tile tt into ring slot tt&3: A 2 issues + B 2 issues
    auto stage_all = [&](int tt) {
        const int s = tt & 3;
        const size_t kbyte = (size_t)tt * (BK * 2);     // 64 B per row chunk
        char* dstA = lds + s * SLOT + tid * 16;
        char* dstB = lds + s * SLOT + 16384 + tid * 16;
#pragma unroll
        for (int i = 0; i < 2; ++i) {
            const int row = i * 128 + srow;
            const char* src = gK + (size_t)(rowbase + row) * (D_DIM * 2) + kbyte + sswz * 16;
            __builtin_amdgcn_global_load_lds(
                (const __attribute__((address_space(1))) void*)src,
                (__attribute__((address_space(3))) void*)(dstA + i * 8192),
                16, 0, 0);
        }
#pragma unroll
        for (int i = 0; i < 2; ++i) {
            const int row = i * 128 + srow;
            const char* src = gK + (size_t)(colbase + row) * (D_DIM * 2) + kbyte + sswz * 16;
            __builtin_amdgcn_global_load_lds(
                (const __attribute__((address_space(1))) void*)src,
                (__attribute__((address_space(3))) void*)(dstB + i * 8192),
                16, 0, 0);
        }
    };

    f32x4 acc[2][4][4] = {};   // [A-half][mi][ni]
    bf16x8 af[4], bf[4];

    auto readA = [&](int s, int a) {
        const char* Ab = lds + s * SLOT;
#pragma unroll
        for (int mi = 0; mi < 4; ++mi) {
            const int row = wr * 128 + a * 64 + mi * 16 + (lane & 15);
            af[mi] = *reinterpret_cast<const bf16x8*>(
                Ab + row * 64 + ((kgrp ^ ((row >> 1) & 3)) << 4));
        }
    };
    auto readB = [&](int s) {
        const char* Bb = lds + s * SLOT + 16384;
#pragma unroll
        for (int ni = 0; ni < 4; ++ni) {
            const int row = wc * 64 + ni * 16 + (lane & 15);
            bf[ni] = *reinterpret_cast<const bf16x8*>(
                Bb + row * 64 + ((kgrp ^ ((row >> 1) & 3)) << 4));
        }
    };
    auto mmaq = [&](int a) {
        __builtin_amdgcn_s_setprio(1);
#pragma unroll
        for (int mi = 0; mi < 4; ++mi)
#pragma unroll
            for (int ni = 0; ni < 4; ++ni)
                acc[a][mi][ni] = __builtin_amdgcn_mfma_f32_16x16x32_bf16(
                    af[mi], bf[ni], acc[a][mi][ni], 0, 0, 0);
        __builtin_amdgcn_s_setprio(0);
    };

    // prologue: tiles 0,1,2 staged; publish tile 0 (leave 1,2 = 8 in flight)
    stage_all(0); stage_all(1); stage_all(2);
    VMCNT(8); BAR();

    for (int t = 0; t < NT; ++t) {
        const int s = t & 3;
        // ---- phase 0: A-half 0 (+ B for whole K-tile)
        readB(s); readA(s, 0);
        BAR(); LGKM0();
        mmaq(0);
        // ---- phase 1: A-half 1; stage t+3; publish t+1
        readA(s, 1);
        if (t + 3 < NT) stage_all(t + 3);
        if (t < NT - 3)       { VMCNT(8); }
        else if (t == NT - 3) { VMCNT(4); }
        else if (t == NT - 2) { VMCNT(0); }
        BAR(); LGKM0();
        mmaq(1);
    }

    // Epilogue. C-frag: col = lane&15, row = (lane>>4)*4 + reg.
    float colpart[4] = {0.0f, 0.0f, 0.0f, 0.0f};
#pragma unroll
    for (int a = 0; a < 2; ++a) {
#pragma unroll
        for (int mi = 0; mi < 4; ++mi) {
#pragma unroll
            for (int reg = 0; reg < 4; ++reg) {
                const int grow = rowbase + wr * 128 + a * 64 + mi * 16 +
                                 ((lane >> 4) << 2) + reg;
                float rowpart = 0.0f;
#pragma unroll
                for (int ni = 0; ni < 4; ++ni) {
                    const int gcol = colbase + wc * 64 + ni * 16 + (lane & 15);
                    float e = __expf(acc[a][mi][ni][reg] * TAU_INV);
                    if (diag && grow == gcol) e = 0.0f;
                    rowpart += e;
                    colpart[ni] += e;
                }
#pragma unroll
                for (int off = 1; off < 16; off <<= 1)
                    rowpart += __shfl_xor(rowpart, off, 64);
                if ((lane & 15) == 0) atomicAdd(&rowsum[grow], rowpart);
            }
        }
    }
    if (!diag) {
#pragma unroll
        for (int ni = 0; ni < 4; ++ni) {
            float cp = colpart[ni];
            cp += __shfl_xor(cp, 16, 64);
            cp += __shfl_xor(cp, 32, 64);
            if (lane < 16)
                atomicAdd(&rowsum[colbase + wc * 64 + ni * 16 + lane], cp);
        }
    }
}

// ---- Kernel C: loss = mean(log(denom) - pos/tau) ---------------------------
__global__ __launch_bounds__(256)
void loss_kernel(const float* __restrict__ rowsum, const float* __restrict__ pos,
                 float* __restrict__ out, int n_total, int n_half) {
    const int t = threadIdx.x;
    float acc = 0.0f;
    for (int r = t; r < n_total; r += 256) {
        const int pi = (r < n_half) ? r : (r - n_half);
        acc += logf(rowsum[r]) - TAU_INV * pos[pi];
    }
    acc = wave_reduce_add(acc);
    __shared__ float ws4[4];
    if ((t & 63) == 0) ws4[t >> 6] = acc;
    __syncthreads();
    if (t == 0) out[0] = (ws4[0] + ws4[1] + ws4[2] + ws4[3]) / (float)n_total;
}

extern "C" void kernel_launch(void* const* d_in, const int* in_sizes, int n_in,
                              void* d_out, int out_size, void* d_ws, size_t ws_size,
                              hipStream_t stream) {
    const float* zi = (const float*)d_in[0];
    const float* zj = (const float*)d_in[1];
    float* out = (float*)d_out;

    const int n_half  = in_sizes[0] / D_DIM;   // 4096
    const int n_total = 2 * n_half;            // 8192

    char* ws = (char*)d_ws;
    __hip_bfloat16* K = (__hip_bfloat16*)ws;
    size_t off = (size_t)n_total * D_DIM * sizeof(__hip_bfloat16);
    float* rowsum = (float*)(ws + off); off += (size_t)n_total * 4;
    float* pos    = (float*)(ws + off); off += (size_t)n_half * 4;

    norm_pos_kernel<<<n_half, 256, 0, stream>>>(zi, zj, K, rowsum, pos, n_half);

    // upper-triangular 256x256 tiles: 32*33/2 = 528 blocks
    simclr_gemm_kernel<<<528, 512, 0, stream>>>(K, rowsum, n_total);

    loss_kernel<<<1, 256, 0, stream>>>(rowsum, pos, out, n_total, n_half);
}

// Round 9
// 119.002 us; speedup vs baseline: 1.1809x; 1.1809x over previous
//
#include <hip/hip_runtime.h>
#include <hip/hip_bf16.h>
#include <cstdint>
#include <math.h>

#define D_DIM 1024
#define TAU_INV 10.0f
#define BK 32
#define NT (D_DIM / BK)        // 32 K-tiles
#define BM 256                 // A-tile rows
#define BN 128                 // B-tile rows (cols of S)
#define SLOT 24576             // ring slot: A 16K + B 8K

typedef __bf16 bf16x8 __attribute__((ext_vector_type(8)));
typedef float f32x4 __attribute__((ext_vector_type(4)));

#define VMCNT(n) asm volatile("s_waitcnt vmcnt(" #n ")" ::: "memory")
#define LGKM0()  asm volatile("s_waitcnt lgkmcnt(0)" ::: "memory")
#define BAR() do { asm volatile("" ::: "memory"); \
                   __builtin_amdgcn_s_barrier();  \
                   asm volatile("" ::: "memory"); } while (0)

__device__ __forceinline__ float wave_reduce_add(float v) {
#pragma unroll
    for (int off = 32; off > 0; off >>= 1) v += __shfl_xor(v, off, 64);
    return v;
}

// ---- Kernel A (fused): normalize both rows -> bf16 K, positives, zero rowsum
__global__ __launch_bounds__(256)
void norm_pos_kernel(const float* __restrict__ zi, const float* __restrict__ zj,
                     __hip_bfloat16* __restrict__ K, float* __restrict__ rowsum,
                     float* __restrict__ pos, int n_half) {
    const int i = blockIdx.x;
    const int t = threadIdx.x;                 // 256 threads x 4 floats = 1024
    float4 a = reinterpret_cast<const float4*>(zi + (size_t)i * D_DIM)[t];
    float4 b = reinterpret_cast<const float4*>(zj + (size_t)i * D_DIM)[t];
    float ssa = a.x*a.x + a.y*a.y + a.z*a.z + a.w*a.w;
    float ssb = b.x*b.x + b.y*b.y + b.z*b.z + b.w*b.w;
    float dab = a.x*b.x + a.y*b.y + a.z*b.z + a.w*b.w;
    ssa = wave_reduce_add(ssa);
    ssb = wave_reduce_add(ssb);
    dab = wave_reduce_add(dab);
    __shared__ float wsa[4], wsb[4], wsd[4];
    if ((t & 63) == 0) { wsa[t>>6] = ssa; wsb[t>>6] = ssb; wsd[t>>6] = dab; }
    __syncthreads();
    const float inva = 1.0f / sqrtf(wsa[0] + wsa[1] + wsa[2] + wsa[3]);
    const float invb = 1.0f / sqrtf(wsb[0] + wsb[1] + wsb[2] + wsb[3]);
    union { __hip_bfloat16 h[4]; uint2 u; } pa, pb;
    pa.h[0] = __float2bfloat16(a.x * inva); pa.h[1] = __float2bfloat16(a.y * inva);
    pa.h[2] = __float2bfloat16(a.z * inva); pa.h[3] = __float2bfloat16(a.w * inva);
    pb.h[0] = __float2bfloat16(b.x * invb); pb.h[1] = __float2bfloat16(b.y * invb);
    pb.h[2] = __float2bfloat16(b.z * invb); pb.h[3] = __float2bfloat16(b.w * invb);
    reinterpret_cast<uint2*>(K + (size_t)i * D_DIM)[t] = pa.u;
    reinterpret_cast<uint2*>(K + (size_t)(i + n_half) * D_DIM)[t] = pb.u;
    if (t == 0) {
        pos[i] = (wsd[0] + wsd[1] + wsd[2] + wsd[3]) * inva * invb;
        rowsum[i] = 0.0f;
        rowsum[i + n_half] = 0.0f;
    }
}

// ---- Kernel B: triangular 256x128 tiles of S = K K^T, 1-barrier pipeline ---
// Tiles: by in [0,32), bx in [2*by, 64) -> 1056 jobs. diag (bx>>1==by):
// row-reduction only, exact diagonal zeroed; others: row + col reduction.
//
// 4 waves (2M x 2N), per-wave output 128x64 = acc[2(A-half)][4][4].
// BK=32, ring-3 LDS (72 KiB) -> 2 blocks/CU (decorrelated barrier domains,
// the consistent winner R4/R7 vs R5/R6/R8).
//
// ONE barrier per K-tile. Per K-tile t (slot s = t%3):
//   readB(4) + readA0(4) + readA1(4)     [12 ds_reads; tile t published at
//                                         BAR(t-1); reads can't hoist above
//                                         BAR's memory clobber]
//   stage_all(t+2)                        [6 gloads, early: ~1.9-K-tile cover]
//   mmaq(0)                               [compiler's counted lgkm waits for
//                                         B+A0 only; A1 latency hides here]
//   LGKM0                                 [drain A1 -- nearly free after mma0;
//                                         makes slot-reuse provably safe]
//   VMCNT(6)                              [leaves only stage(t+2): publishes
//                                         tile t+1 at the BAR]
//   BAR
//   mmaq(1)                               [operands in regs; overlaps next
//                                         iteration's read issue]
// Safety: (residency) VMCNT(6)+BAR at t-1 -> tile t resident for all waves.
// (slot reuse) stage(t+2)@iter-t writes slot (t-1)%3; every wave's reads of
// that slot completed before its LGKM0@t-1 < its BAR(t-1) < any wave's
// stage issue @iter-t. Tail: t==NT-2 VMCNT(0); t==NT-1 no wait/BAR.
// LDS swizzle (R4/R7-verified, 0 conflicts): 16B slot_phys = kgrp^((row>>1)&3),
// inverse-applied on the global staging source (rule #21).
__global__ __launch_bounds__(256, 2)
void simclr_gemm_kernel(const __hip_bfloat16* __restrict__ Kmat,
                        float* __restrict__ rowsum, int n_total) {
    __shared__ char lds[73728];

    const int tid  = threadIdx.x;
    const int lane = tid & 63;
    const int wave = tid >> 6;          // 0..3
    const int wr = wave >> 1;           // 0..1  (A rows wr*128)
    const int wc = wave & 1;            // 0..1  (B cols wc*64)
    const int kgrp = lane >> 4;         // 16B k-slot within 64B row

    // bijective XCD swizzle: nwg = 1056 = 8 * 132
    const int wg = (blockIdx.x & 7) * 132 + (blockIdx.x >> 3);

    // decode wg -> (by, bx): by in [0,32), bx in [2*by, 64)
    int by = 0, start = 0;
    while (wg >= start + (64 - 2 * by)) { start += 64 - 2 * by; ++by; }
    const int bx = 2 * by + (wg - start);
    const bool diag = ((bx >> 1) == by);
    const int rowbase = by * BM;
    const int colbase = bx * BN;

    const char* gK = reinterpret_cast<const char*>(Kmat);
    const int srow = tid >> 2;                          // 0..63 per 4KB chunk
    const int sswz = (tid & 3) ^ ((srow >> 1) & 3);     // inverse-swizzled slot

    // stage full K-tile tt into ring slot tt%3: A 4 chunks + B 2 chunks
    auto stage_all = [&](int tt) {
        const int s = tt % 3;
        const size_t kbyte = (size_t)tt * (BK * 2);     // 64 B per row chunk
        char* dstA = lds + s * SLOT + tid * 16;
        char* dstB = lds + s * SLOT + 16384 + tid * 16;
#pragma unroll
        for (int i = 0; i < 4; ++i) {
            const int row = i * 64 + srow;
            const char* src = gK + (size_t)(rowbase + row) * (D_DIM * 2) + kbyte + sswz * 16;
            __builtin_amdgcn_global_load_lds(
                (const __attribute__((address_space(1))) void*)src,
                (__attribute__((address_space(3))) void*)(dstA + i * 4096),
                16, 0, 0);
        }
#pragma unroll
        for (int i = 0; i < 2; ++i) {
            const int row = i * 64 + srow;
            const char* src = gK + (size_t)(colbase + row) * (D_DIM * 2) + kbyte + sswz * 16;
            __builtin_amdgcn_global_load_lds(
                (const __attribute__((address_space(1))) void*)src,
                (__attribute__((address_space(3))) void*)(dstB + i * 4096),
                16, 0, 0);
        }
    };

    f32x4 acc[2][4][4] = {};   // [A-half][mi][ni]
    bf16x8 af0[4], af1[4], bf[4];

    auto readA = [&](int s, int a, bf16x8* dst) {
        const char* Ab = lds + s * SLOT;
#pragma unroll
        for (int mi = 0; mi < 4; ++mi) {
            const int row = wr * 128 + a * 64 + mi * 16 + (lane & 15);
            dst[mi] = *reinterpret_cast<const bf16x8*>(
                Ab + row * 64 + ((kgrp ^ ((row >> 1) & 3)) << 4));
        }
    };
    auto readB = [&](int s) {
        const char* Bb = lds + s * SLOT + 16384;
#pragma unroll
        for (int ni = 0; ni < 4; ++ni) {
            const int row = wc * 64 + ni * 16 + (lane & 15);
            bf[ni] = *reinterpret_cast<const bf16x8*>(
                Bb + row * 64 + ((kgrp ^ ((row >> 1) & 3)) << 4));
        }
    };
    auto mmaq = [&](int a, const bf16x8* af) {
        __builtin_amdgcn_s_setprio(1);
#pragma unroll
        for (int mi = 0; mi < 4; ++mi)
#pragma unroll
            for (int ni = 0; ni < 4; ++ni)
                acc[a][mi][ni] = __builtin_amdgcn_mfma_f32_16x16x32_bf16(
                    af[mi], bf[ni], acc[a][mi][ni], 0, 0, 0);
        __builtin_amdgcn_s_setprio(0);
    };

    // prologue: tiles 0,1 staged; publish tile 0 (leave tile 1's 6 in flight)
    stage_all(0); stage_all(1);
    VMCNT(6); BAR();

    for (int t = 0; t < NT; ++t) {
        const int s = t % 3;
        readB(s); readA(s, 0, af0); readA(s, 1, af1);   // 12 ds_reads up-front
        if (t + 2 < NT) stage_all(t + 2);               // early prefetch issue
        mmaq(0, af0);                                   // A1 latency hides here
        if (t < NT - 1) {
            LGKM0();                                    // drain own reads pre-BAR
            if (t < NT - 2) { VMCNT(6); } else { VMCNT(0); }
            BAR();                                      // publish tile t+1
        }
        mmaq(1, af1);                                   // regs only; overlaps
    }                                                   // next read issue

    // Epilogue. C-frag: col = lane&15, row = (lane>>4)*4 + reg.
    float colpart[4] = {0.0f, 0.0f, 0.0f, 0.0f};
#pragma unroll
    for (int a = 0; a < 2; ++a) {
#pragma unroll
        for (int mi = 0; mi < 4; ++mi) {
#pragma unroll
            for (int reg = 0; reg < 4; ++reg) {
                const int grow = rowbase + wr * 128 + a * 64 + mi * 16 +
                                 ((lane >> 4) << 2) + reg;
                float rowpart = 0.0f;
#pragma unroll
                for (int ni = 0; ni < 4; ++ni) {
                    const int gcol = colbase + wc * 64 + ni * 16 + (lane & 15);
                    float e = __expf(acc[a][mi][ni][reg] * TAU_INV);
                    if (diag && grow == gcol) e = 0.0f;
                    rowpart += e;
                    colpart[ni] += e;
                }
#pragma unroll
                for (int off = 1; off < 16; off <<= 1)
                    rowpart += __shfl_xor(rowpart, off, 64);
                if ((lane & 15) == 0) atomicAdd(&rowsum[grow], rowpart);
            }
        }
    }
    if (!diag) {
#pragma unroll
        for (int ni = 0; ni < 4; ++ni) {
            float cp = colpart[ni];
            cp += __shfl_xor(cp, 16, 64);
            cp += __shfl_xor(cp, 32, 64);
            if (lane < 16)
                atomicAdd(&rowsum[colbase + wc * 64 + ni * 16 + lane], cp);
        }
    }
}

// ---- Kernel C: loss = mean(log(denom) - pos/tau) ---------------------------
__global__ __launch_bounds__(256)
void loss_kernel(const float* __restrict__ rowsum, const float* __restrict__ pos,
                 float* __restrict__ out, int n_total, int n_half) {
    const int t = threadIdx.x;
    float acc = 0.0f;
    for (int r = t; r < n_total; r += 256) {
        const int pi = (r < n_half) ? r : (r - n_half);
        acc += logf(rowsum[r]) - TAU_INV * pos[pi];
    }
    acc = wave_reduce_add(acc);
    __shared__ float ws4[4];
    if ((t & 63) == 0) ws4[t >> 6] = acc;
    __syncthreads();
    if (t == 0) out[0] = (ws4[0] + ws4[1] + ws4[2] + ws4[3]) / (float)n_total;
}

extern "C" void kernel_launch(void* const* d_in, const int* in_sizes, int n_in,
                              void* d_out, int out_size, void* d_ws, size_t ws_size,
                              hipStream_t stream) {
    const float* zi = (const float*)d_in[0];
    const float* zj = (const float*)d_in[1];
    float* out = (float*)d_out;

    const int n_half  = in_sizes[0] / D_DIM;   // 4096
    const int n_total = 2 * n_half;            // 8192

    char* ws = (char*)d_ws;
    __hip_bfloat16* K = (__hip_bfloat16*)ws;
    size_t off = (size_t)n_total * D_DIM * sizeof(__hip_bfloat16);
    float* rowsum = (float*)(ws + off); off += (size_t)n_total * 4;
    float* pos    = (float*)(ws + off); off += (size_t)n_half * 4;

    norm_pos_kernel<<<n_half, 256, 0, stream>>>(zi, zj, K, rowsum, pos, n_half);

    // triangular 256x128 tiles: sum_{by=0}^{31} (64 - 2*by) = 1056 blocks
    simclr_gemm_kernel<<<1056, 256, 0, stream>>>(K, rowsum, n_total);

    loss_kernel<<<1, 256, 0, stream>>>(rowsum, pos, out, n_total, n_half);
}

// Round 10
// 107.937 us; speedup vs baseline: 1.3020x; 1.1025x over previous
//
#include <hip/hip_runtime.h>
#include <hip/hip_bf16.h>
#include <cstdint>
#include <math.h>

#define D_DIM 1024
#define TAU_INV 10.0f
#define BK 32
#define NT (D_DIM / BK)        // 32 K-tiles
#define BM 256                 // A-tile rows
#define BN 128                 // B-tile rows (cols of S)
#define SLOT 24576             // ring slot: A 16K + B 8K

typedef __bf16 bf16x8 __attribute__((ext_vector_type(8)));
typedef float f32x4 __attribute__((ext_vector_type(4)));

#define VMCNT(n) asm volatile("s_waitcnt vmcnt(" #n ")" ::: "memory")
#define LGKM0()  asm volatile("s_waitcnt lgkmcnt(0)" ::: "memory")
#define BAR() do { asm volatile("" ::: "memory"); \
                   __builtin_amdgcn_s_barrier();  \
                   asm volatile("" ::: "memory"); } while (0)

__device__ __forceinline__ float wave_reduce_add(float v) {
#pragma unroll
    for (int off = 32; off > 0; off >>= 1) v += __shfl_xor(v, off, 64);
    return v;
}

// ---- Kernel A (fused): normalize both rows -> bf16 K, positives, zero rowsum
__global__ __launch_bounds__(256)
void norm_pos_kernel(const float* __restrict__ zi, const float* __restrict__ zj,
                     __hip_bfloat16* __restrict__ K, float* __restrict__ rowsum,
                     float* __restrict__ pos, int n_half) {
    const int i = blockIdx.x;
    const int t = threadIdx.x;                 // 256 threads x 4 floats = 1024
    float4 a = reinterpret_cast<const float4*>(zi + (size_t)i * D_DIM)[t];
    float4 b = reinterpret_cast<const float4*>(zj + (size_t)i * D_DIM)[t];
    float ssa = a.x*a.x + a.y*a.y + a.z*a.z + a.w*a.w;
    float ssb = b.x*b.x + b.y*b.y + b.z*b.z + b.w*b.w;
    float dab = a.x*b.x + a.y*b.y + a.z*b.z + a.w*b.w;
    ssa = wave_reduce_add(ssa);
    ssb = wave_reduce_add(ssb);
    dab = wave_reduce_add(dab);
    __shared__ float wsa[4], wsb[4], wsd[4];
    if ((t & 63) == 0) { wsa[t>>6] = ssa; wsb[t>>6] = ssb; wsd[t>>6] = dab; }
    __syncthreads();
    const float inva = 1.0f / sqrtf(wsa[0] + wsa[1] + wsa[2] + wsa[3]);
    const float invb = 1.0f / sqrtf(wsb[0] + wsb[1] + wsb[2] + wsb[3]);
    union { __hip_bfloat16 h[4]; uint2 u; } pa, pb;
    pa.h[0] = __float2bfloat16(a.x * inva); pa.h[1] = __float2bfloat16(a.y * inva);
    pa.h[2] = __float2bfloat16(a.z * inva); pa.h[3] = __float2bfloat16(a.w * inva);
    pb.h[0] = __float2bfloat16(b.x * invb); pb.h[1] = __float2bfloat16(b.y * invb);
    pb.h[2] = __float2bfloat16(b.z * invb); pb.h[3] = __float2bfloat16(b.w * invb);
    reinterpret_cast<uint2*>(K + (size_t)i * D_DIM)[t] = pa.u;
    reinterpret_cast<uint2*>(K + (size_t)(i + n_half) * D_DIM)[t] = pb.u;
    if (t == 0) {
        pos[i] = (wsd[0] + wsd[1] + wsd[2] + wsd[3]) * inva * invb;
        rowsum[i] = 0.0f;
        rowsum[i + n_half] = 0.0f;
    }
}

// ---- Kernel B: triangular 256x128 tiles, 8 waves of 64x64, 1-barrier -------
// Device-pipe audit of R9 (same schedule, 4 waves of 128x64): MFMA 28%, LDS
// 32%, VALU 22% -- latency/sync-bound, no pipe saturated. Fix: 16 waves/CU
// (2 blocks x 8 waves, 4 waves/SIMD) for latency hiding; per-wave tile 64x64
// keeps acc at 64 regs so 4 waves/SIMD fits (launch_bounds caps at 128).
//
// Tiles: by in [0,32), bx in [2*by, 64) -> 1056 jobs. diag (bx>>1==by):
// row-reduction only, exact diagonal zeroed; others: row + col reduction.
//
// Per K-tile t (slot s = t%3), R9-proven 1-barrier discipline:
//   readA(4) + readB01(2) + readB23(2)    [12->8 ds_reads, tile t published
//                                          at BAR(t-1)]
//   stage_all(t+2)                        [3 gloads/thread, ~2-K-tile cover]
//   mma ni=0,1 (8 MFMA)                   [compiler lgkm waits 6 reads only;
//                                          bf2/bf3 latency hides here]
//   LGKM0 ; VMCNT(3) ; BAR                [drain own reads; leave only
//                                          stage(t+2) -> publishes tile t+1]
//   mma ni=2,3 (8 MFMA)                   [regs only; overlaps next iter]
// Residency induction and slot-reuse proof identical to R9 (absmax 0 since R4).
// Tail: t==NT-2 VMCNT(0); t==NT-1 no wait/BAR.
// LDS swizzle (R4/R7/R9-verified, 0 conflicts): 16B slot_phys = kgrp ^
// ((row>>1)&3), inverse-applied on the global staging source (rule #21).
__global__ __launch_bounds__(512, 4)
void simclr_gemm_kernel(const __hip_bfloat16* __restrict__ Kmat,
                        float* __restrict__ rowsum, int n_total) {
    __shared__ char lds[73728];

    const int tid  = threadIdx.x;
    const int lane = tid & 63;
    const int wave = tid >> 6;          // 0..7
    const int wr = wave >> 1;           // 0..3  (A rows wr*64)
    const int wc = wave & 1;            // 0..1  (B cols wc*64)
    const int kgrp = lane >> 4;         // 16B k-slot within 64B row

    // bijective XCD swizzle: nwg = 1056 = 8 * 132
    const int wg = (blockIdx.x & 7) * 132 + (blockIdx.x >> 3);

    // decode wg -> (by, bx): by in [0,32), bx in [2*by, 64)
    int by = 0, start = 0;
    while (wg >= start + (64 - 2 * by)) { start += 64 - 2 * by; ++by; }
    const int bx = 2 * by + (wg - start);
    const bool diag = ((bx >> 1) == by);
    const int rowbase = by * BM;
    const int colbase = bx * BN;

    const char* gK = reinterpret_cast<const char*>(Kmat);
    const int srow = tid >> 2;                          // 0..127 per 8KB issue
    const int sswz = (tid & 3) ^ ((srow >> 1) & 3);     // inverse-swizzled slot

    // stage full K-tile tt into ring slot tt%3: A 2 issues + B 1 issue
    auto stage_all = [&](int tt) {
        const int s = tt % 3;
        const size_t kbyte = (size_t)tt * (BK * 2);     // 64 B per row chunk
        char* dstA = lds + s * SLOT + tid * 16;
        char* dstB = lds + s * SLOT + 16384 + tid * 16;
#pragma unroll
        for (int i = 0; i < 2; ++i) {
            const int row = i * 128 + srow;
            const char* src = gK + (size_t)(rowbase + row) * (D_DIM * 2) + kbyte + sswz * 16;
            __builtin_amdgcn_global_load_lds(
                (const __attribute__((address_space(1))) void*)src,
                (__attribute__((address_space(3))) void*)(dstA + i * 8192),
                16, 0, 0);
        }
        {
            const char* src = gK + (size_t)(colbase + srow) * (D_DIM * 2) + kbyte + sswz * 16;
            __builtin_amdgcn_global_load_lds(
                (const __attribute__((address_space(1))) void*)src,
                (__attribute__((address_space(3))) void*)dstB,
                16, 0, 0);
        }
    };

    f32x4 acc[4][4] = {};      // [mi][ni]
    bf16x8 af[4], bf[4];

    auto readA = [&](int s) {
        const char* Ab = lds + s * SLOT;
#pragma unroll
        for (int mi = 0; mi < 4; ++mi) {
            const int row = wr * 64 + mi * 16 + (lane & 15);
            af[mi] = *reinterpret_cast<const bf16x8*>(
                Ab + row * 64 + ((kgrp ^ ((row >> 1) & 3)) << 4));
        }
    };
    auto readB2 = [&](int s, int h) {   // bf[h*2], bf[h*2+1]
        const char* Bb = lds + s * SLOT + 16384;
#pragma unroll
        for (int ni = h * 2; ni < h * 2 + 2; ++ni) {
            const int row = wc * 64 + ni * 16 + (lane & 15);
            bf[ni] = *reinterpret_cast<const bf16x8*>(
                Bb + row * 64 + ((kgrp ^ ((row >> 1) & 3)) << 4));
        }
    };
    auto mma_half = [&](int h) {        // ni = h*2, h*2+1
        __builtin_amdgcn_s_setprio(1);
#pragma unroll
        for (int mi = 0; mi < 4; ++mi)
#pragma unroll
            for (int ni = h * 2; ni < h * 2 + 2; ++ni)
                acc[mi][ni] = __builtin_amdgcn_mfma_f32_16x16x32_bf16(
                    af[mi], bf[ni], acc[mi][ni], 0, 0, 0);
        __builtin_amdgcn_s_setprio(0);
    };

    // prologue: tiles 0,1 staged; publish tile 0 (leave tile 1's 3 in flight)
    stage_all(0); stage_all(1);
    VMCNT(3); BAR();

    for (int t = 0; t < NT; ++t) {
        const int s = t % 3;
        readA(s); readB2(s, 0); readB2(s, 1);           // 8 ds_reads up-front
        if (t + 2 < NT) stage_all(t + 2);               // early prefetch issue
        mma_half(0);                                    // bf2/3 latency hides
        if (t < NT - 1) {
            LGKM0();                                    // drain own reads pre-BAR
            if (t < NT - 2) { VMCNT(3); } else { VMCNT(0); }
            BAR();                                      // publish tile t+1
        }
        mma_half(1);                                    // regs only; overlaps
    }                                                   // next read issue

    // Epilogue. C-frag: col = lane&15, row = (lane>>4)*4 + reg.
    float colpart[4] = {0.0f, 0.0f, 0.0f, 0.0f};
#pragma unroll
    for (int mi = 0; mi < 4; ++mi) {
#pragma unroll
        for (int reg = 0; reg < 4; ++reg) {
            const int grow = rowbase + wr * 64 + mi * 16 + ((lane >> 4) << 2) + reg;
            float rowpart = 0.0f;
#pragma unroll
            for (int ni = 0; ni < 4; ++ni) {
                const int gcol = colbase + wc * 64 + ni * 16 + (lane & 15);
                float e = __expf(acc[mi][ni][reg] * TAU_INV);
                if (diag && grow == gcol) e = 0.0f;
                rowpart += e;
                colpart[ni] += e;
            }
#pragma unroll
            for (int off = 1; off < 16; off <<= 1)
                rowpart += __shfl_xor(rowpart, off, 64);
            if ((lane & 15) == 0) atomicAdd(&rowsum[grow], rowpart);
        }
    }
    if (!diag) {
#pragma unroll
        for (int ni = 0; ni < 4; ++ni) {
            float cp = colpart[ni];
            cp += __shfl_xor(cp, 16, 64);
            cp += __shfl_xor(cp, 32, 64);
            if (lane < 16)
                atomicAdd(&rowsum[colbase + wc * 64 + ni * 16 + lane], cp);
        }
    }
}

// ---- Kernel C: loss = mean(log(denom) - pos/tau) ---------------------------
__global__ __launch_bounds__(256)
void loss_kernel(const float* __restrict__ rowsum, const float* __restrict__ pos,
                 float* __restrict__ out, int n_total, int n_half) {
    const int t = threadIdx.x;
    float acc = 0.0f;
    for (int r = t; r < n_total; r += 256) {
        const int pi = (r < n_half) ? r : (r - n_half);
        acc += logf(rowsum[r]) - TAU_INV * pos[pi];
    }
    acc = wave_reduce_add(acc);
    __shared__ float ws4[4];
    if ((t & 63) == 0) ws4[t >> 6] = acc;
    __syncthreads();
    if (t == 0) out[0] = (ws4[0] + ws4[1] + ws4[2] + ws4[3]) / (float)n_total;
}

extern "C" void kernel_launch(void* const* d_in, const int* in_sizes, int n_in,
                              void* d_out, int out_size, void* d_ws, size_t ws_size,
                              hipStream_t stream) {
    const float* zi = (const float*)d_in[0];
    const float* zj = (const float*)d_in[1];
    float* out = (float*)d_out;

    const int n_half  = in_sizes[0] / D_DIM;   // 4096
    const int n_total = 2 * n_half;            // 8192

    char* ws = (char*)d_ws;
    __hip_bfloat16* K = (__hip_bfloat16*)ws;
    size_t off = (size_t)n_total * D_DIM * sizeof(__hip_bfloat16);
    float* rowsum = (float*)(ws + off); off += (size_t)n_total * 4;
    float* pos    = (float*)(ws + off); off += (size_t)n_half * 4;

    norm_pos_kernel<<<n_half, 256, 0, stream>>>(zi, zj, K, rowsum, pos, n_half);

    // triangular 256x128 tiles: sum_{by=0}^{31} (64 - 2*by) = 1056 blocks
    simclr_gemm_kernel<<<1056, 512, 0, stream>>>(K, rowsum, n_total);

    loss_kernel<<<1, 256, 0, stream>>>(rowsum, pos, out, n_total, n_half);
}